// Round 8
// baseline (1762.488 us; speedup 1.0000x reference)
//
#include <hip/hip_runtime.h>
#include <cstdint>
#include <cstddef>

#define B_   32
#define T_   128
#define H_   1024
#define V_   32000
#define NBLK 64
#define NTHR 768       // 12 waves: (gate 0..2) x (batch-half 0..1) x (k-half 0..1)
#define JB   16        // columns per block -> 48 W rows = 3 gates x 16-row MFMA strip
#define BH_  (B_*H_)   // 32768 elements per h buffer

typedef short  short8  __attribute__((ext_vector_type(8)));
typedef short  short4v __attribute__((ext_vector_type(4)));
typedef float  f32x4   __attribute__((ext_vector_type(4)));

// LDS byte layout:
//   hhi [32 b][2048 B]  65536   (bf16 hi of h, XOR-swizzled 16B slots)
//   hlo [32 b][2048 B]  65536   (bf16 lo)
//   ghp f32 [2 kh][48 row][33]  12672  (k-half partial gh, stride-33 anti-conflict)
#define LDS_HHI   0
#define LDS_HLO   65536
#define LDS_GHP   131072
#define LDS_BYTES (131072 + 2*48*33*4)   // 143744

__device__ __forceinline__ unsigned short bf16_rtn(float f) {
    unsigned u = __float_as_uint(f);
    u += 0x7FFFu + ((u >> 16) & 1u);
    return (unsigned short)(u >> 16);
}

__global__ __launch_bounds__(NTHR) void gru_persist(
    const float* __restrict__ Whh,   // (3072,1024)
    const float* __restrict__ bhh,   // (3072)
    const float* __restrict__ Wih,   // (3072,32000)
    const float* __restrict__ bih,   // (3072)
    const int*   __restrict__ xs,    // (B,T)
    unsigned*    __restrict__ hpk,   // T_ x (B,H) packed (hi16|lo16) h buffers
    int*         __restrict__ flags, // (NBLK*32) zeroed before launch
    float*       __restrict__ outp,  // (B,T,H)
    float*       __restrict__ hidout)// (B,H)
{
    extern __shared__ char lds[];
    char*  hhi = lds + LDS_HHI;
    char*  hlo = lds + LDS_HLO;
    float* ghp = (float*)(lds + LDS_GHP);

    const int tid  = threadIdx.x;
    const int bid  = (int)blockIdx.x;
    const int j0   = bid * JB;
    const int lane = tid & 63;
    const int wid  = tid >> 6;         // 0..11
    const int g    = wid >> 2;         // gate 0..2
    const int bh   = (wid >> 1) & 1;   // batch half
    const int kh   = wid & 1;          // k half

    // ---- W A-fragments -> registers, once. wA[kkl]: lane holds
    // W[g*H + j0 + (lane&15)][kk*32 + (lane>>4)*8 + j], kk = kh*16+kkl ----
    short8 wAhi[16], wAlo[16];
    {
        const int   arow = lane & 15;
        const int   q    = lane >> 4;
        const float* wr  = Whh + (size_t)(g * H_ + j0 + arow) * H_;
        #pragma unroll
        for (int kkl = 0; kkl < 16; ++kkl) {
            const int kk = kh * 16 + kkl;
            const float4 w0 = *(const float4*)(wr + kk * 32 + q * 8);
            const float4 w1 = *(const float4*)(wr + kk * 32 + q * 8 + 4);
            const float wv[8] = {w0.x, w0.y, w0.z, w0.w, w1.x, w1.y, w1.z, w1.w};
            short8 hi8, lo8;
            #pragma unroll
            for (int j = 0; j < 8; ++j) {
                const unsigned short h = bf16_rtn(wv[j]);
                const float hf = __uint_as_float((unsigned)h << 16);
                hi8[j] = (short)h;
                lo8[j] = (short)bf16_rtn(wv[j] - hf);
            }
            wAhi[kkl] = hi8;
            wAlo[kkl] = lo8;
        }
    }

    // ---- B-frag LDS addressing constants (lane&15 = batch row within half) ----
    const int brow  = bh * 16 + (lane & 15);
    const int bq    = lane >> 4;
    const int bbase = brow * 2048;
    const int bhash = (lane & 7) << 4;   // == (brow&7)<<4

    // ---- gate-thread constants (tid<512): jj = tid&15 col, b = tid>>4 batch ----
    const int jj = tid & 15;
    const int b  = tid >> 4;
    float bih0 = 0.f, bih1 = 0.f, bih2 = 0.f;
    float bhh0 = 0.f, bhh1 = 0.f, bhh2 = 0.f;
    float nxg0 = 0.f, nxg1 = 0.f, nxg2 = 0.f;
    float hold = 0.f;
    size_t gr0 = 0, gr1 = 0, gr2 = 0;
    if (tid < 512) {
        gr0 = (size_t)(0 * H_ + j0 + jj) * V_;
        gr1 = (size_t)(1 * H_ + j0 + jj) * V_;
        gr2 = (size_t)(2 * H_ + j0 + jj) * V_;
        bih0 = bih[0 * H_ + j0 + jj];
        bih1 = bih[1 * H_ + j0 + jj];
        bih2 = bih[2 * H_ + j0 + jj];
        bhh0 = bhh[0 * H_ + j0 + jj];
        bhh1 = bhh[1 * H_ + j0 + jj];
        bhh2 = bhh[2 * H_ + j0 + jj];
        const int tok = xs[b * T_];      // t=0 gather prefetch
        nxg0 = Wih[gr0 + tok];
        nxg1 = Wih[gr1 + tok];
        nxg2 = Wih[gr2 + tok];
    }

    __syncthreads();

    #pragma unroll 1
    for (int t = 0; t < T_; ++t) {
        const unsigned* hp_prev = hpk + (size_t)(t - 1) * BH_;  // valid t>0
        unsigned*       hp_cur  = hpk + (size_t)t * BH_;

        // consume this step's gather; issue next step's (full step of cover)
        const float cg0 = nxg0, cg1 = nxg1, cg2 = nxg2;
        if (tid < 512 && t + 1 < T_) {
            const int tok = xs[b * T_ + t + 1];
            nxg0 = Wih[gr0 + tok];
            nxg1 = Wih[gr1 + tok];
            nxg2 = Wih[gr2 + tok];
        }

        if (t > 0) {
            // ---- rendezvous: 1 thread per producer flag (64 flags) ----
            if (tid < 64) {
                const int* fp = flags + tid * 32;
                int v;
                do {
                    v = __hip_atomic_load(fp, __ATOMIC_RELAXED,
                                          __HIP_MEMORY_SCOPE_AGENT);
                } while (v < t);
            }
            __syncthreads();

            // ---- stage packed h -> swizzled split-bf16 LDS ----
            // chunk c (uint4 = 4 packed cols): b = c>>8, k0 = (c&255)*4
            uint4 st[11];
            #pragma unroll
            for (int i = 0; i < 11; ++i) {
                const int c = tid + i * NTHR;
                if (c < 8192) st[i] = ((const uint4*)hp_prev)[c];
            }
            #pragma unroll
            for (int i = 0; i < 11; ++i) {
                const int c = tid + i * NTHR;
                if (c < 8192) {
                    const int bb  = c >> 8;
                    const int k0  = (c & 255) * 4;
                    const int off = bb * 2048 + ((k0 * 2) ^ ((bb & 7) << 4));
                    short4v hi4, lo4;
                    hi4[0] = (short)(st[i].x >> 16); lo4[0] = (short)(st[i].x & 0xFFFFu);
                    hi4[1] = (short)(st[i].y >> 16); lo4[1] = (short)(st[i].y & 0xFFFFu);
                    hi4[2] = (short)(st[i].z >> 16); lo4[2] = (short)(st[i].z & 0xFFFFu);
                    hi4[3] = (short)(st[i].w >> 16); lo4[3] = (short)(st[i].w & 0xFFFFu);
                    *(short4v*)(hhi + off) = hi4;
                    *(short4v*)(hlo + off) = lo4;
                }
            }
            __syncthreads();
        }

        // ---- MFMA: 3 passes split-bf16, 16 k-steps per wave (k-half) ----
        f32x4 ahh = {0.f, 0.f, 0.f, 0.f};
        f32x4 ahl = {0.f, 0.f, 0.f, 0.f};
        f32x4 alh = {0.f, 0.f, 0.f, 0.f};
        if (t > 0) {
            #pragma unroll
            for (int kkl = 0; kkl < 16; ++kkl) {
                const int kk  = kh * 16 + kkl;
                const int off = (kk * 64 + bq * 16) ^ bhash;
                const short8 bhi8 = *(const short8*)(hhi + bbase + off);
                const short8 blo8 = *(const short8*)(hlo + bbase + off);
                ahh = __builtin_amdgcn_mfma_f32_16x16x32_bf16(wAhi[kkl], bhi8, ahh, 0, 0, 0);
                ahl = __builtin_amdgcn_mfma_f32_16x16x32_bf16(wAhi[kkl], blo8, ahl, 0, 0, 0);
                alh = __builtin_amdgcn_mfma_f32_16x16x32_bf16(wAlo[kkl], bhi8, alh, 0, 0, 0);
            }
        }

        // ---- k-half partials -> LDS (C layout: col=lane&15=batch, row=(lane>>4)*4+r) ----
        {
            const int bcol = bh * 16 + (lane & 15);
            #pragma unroll
            for (int r = 0; r < 4; ++r) {
                const int m = (lane >> 4) * 4 + r;
                ghp[kh * 1584 + (g * 16 + m) * 33 + bcol] = ahh[r] + ahl[r] + alh[r];
            }
        }
        __syncthreads();

        // ---- gate math + publish (threads 0..511) ----
        if (tid < 512) {
            float hr = bhh0, hz = bhh1, hn = bhh2;
            if (t > 0) {
                hr += ghp[(0 * 16 + jj) * 33 + b] + ghp[1584 + (0 * 16 + jj) * 33 + b];
                hz += ghp[(1 * 16 + jj) * 33 + b] + ghp[1584 + (1 * 16 + jj) * 33 + b];
                hn += ghp[(2 * 16 + jj) * 33 + b] + ghp[1584 + (2 * 16 + jj) * 33 + b];
            }
            const float rg = 1.f / (1.f + __expf(-(cg0 + bih0 + hr)));
            const float zg = 1.f / (1.f + __expf(-(cg1 + bih1 + hz)));
            const float tn = cg2 + bih2 + rg * hn;
            const float e  = __expf(-2.f * fabsf(tn));
            const float m  = (1.f - e) / (1.f + e);
            const float ng = copysignf(m, tn);           // tanh, inf-safe
            const float hnew = (1.f - zg) * ng + zg * hold;
            hold = hnew;                                  // h_old stays in-register

            const unsigned short hh = bf16_rtn(hnew);
            const float hf = __uint_as_float((unsigned)hh << 16);
            const unsigned short hl = bf16_rtn(hnew - hf);
            const unsigned pk = ((unsigned)hh << 16) | (unsigned)hl;
            // device-coherent write-through (sc1); relaxed -> no wbl2/inv
            __hip_atomic_store(hp_cur + (size_t)b * H_ + j0 + jj, pk,
                               __ATOMIC_RELAXED, __HIP_MEMORY_SCOPE_AGENT);
            outp[((size_t)b * T_ + t) * H_ + j0 + jj] = hnew;
            if (t == T_ - 1) hidout[(size_t)b * H_ + j0 + jj] = hnew;
        }

        // ---- publish: syncthreads drains all sc1 stores (vmcnt(0)), then flag ----
        __syncthreads();
        if (tid == 0) {
            __hip_atomic_store(&flags[bid * 32], t + 1,
                               __ATOMIC_RELAXED, __HIP_MEMORY_SCOPE_AGENT);
        }
    }
}

extern "C" void kernel_launch(void* const* d_in, const int* in_sizes, int n_in,
                              void* d_out, int out_size, void* d_ws, size_t ws_size,
                              hipStream_t stream) {
    const int*   xs  = (const int*)  d_in[0];
    const float* Wih = (const float*)d_in[1];
    const float* Whh = (const float*)d_in[2];
    const float* bih = (const float*)d_in[3];
    const float* bhh = (const float*)d_in[4];

    float* outp = (float*)d_out;
    float* hid  = outp + (size_t)B_ * T_ * H_;

    unsigned* hpk   = (unsigned*)d_ws;                   // 128 x 128 KB = 16 MB
    int*      flags = (int*)(hpk + (size_t)T_ * BH_);

    // zero the barrier flags every launch (graph-replay deterministic)
    (void)hipMemsetAsync(flags, 0, (size_t)NBLK * 32 * sizeof(int), stream);

    const size_t LDSB = LDS_BYTES;                       // 143744 B
    (void)hipFuncSetAttribute((const void*)gru_persist,
                              hipFuncAttributeMaxDynamicSharedMemorySize,
                              (int)LDSB);

    gru_persist<<<NBLK, NTHR, LDSB, stream>>>(
        Whh, bhh, Wih, bih, xs, hpk, flags, outp, hid);

    (void)in_sizes; (void)n_in; (void)out_size; (void)ws_size;
}

// Round 9
// 1252.940 us; speedup vs baseline: 1.4067x; 1.4067x over previous
//
#include <hip/hip_runtime.h>
#include <cstdint>
#include <cstddef>

#define B_   32
#define T_   128
#define H_   1024
#define V_   32000
#define NBT  (B_*T_)   // 4096
#define G3H  (3*H_)    // 3072
#define NBLK 64
#define NTHR 768       // 12 waves: (gate 0..2) x (batch-half 0..1) x (k-half 0..1)
#define JB   16        // columns per block -> 48 W rows
#define BH_  (B_*H_)   // 32768 elements per h buffer

typedef short  short8  __attribute__((ext_vector_type(8)));
typedef short  short4v __attribute__((ext_vector_type(4)));
typedef float  f32x4   __attribute__((ext_vector_type(4)));

// GRU LDS byte layout:
//   hhi [32 b][2048 B]  65536   (bf16 hi of h, XOR-swizzled 16B slots)
//   hlo [32 b][2048 B]  65536   (bf16 lo)
//   ghp f32 [2 kh][48 row][33]  12672
#define LDS_HHI   0
#define LDS_HLO   65536
#define LDS_GHP   131072
#define LDS_BYTES (131072 + 2*48*33*4)   // 143744

#define EMB_LDS (V_*4 + NBT*4)           // 144384

__device__ __forceinline__ unsigned short bf16_rtn(float f) {
    unsigned u = __float_as_uint(f);
    u += 0x7FFFu + ((u >> 16) & 1u);
    return (unsigned short)(u >> 16);
}

// ---------- prepass: gxT[r][bt] = Wih[r][tok[bt]] + bih[r] ----------
// One block per W_ih row: stream the 128 KB row coalesced into LDS once,
// then 4096 LDS lookups + one coalesced 16 KB store. HBM: W_ih read exactly
// once, sequentially (393 MB), vs 805 MB of random 64B lines for the
// per-step gather.
__global__ __launch_bounds__(1024) void gru_embed(
    const float* __restrict__ Wih,   // (3072,32000)
    const float* __restrict__ bih,   // (3072)
    const int*   __restrict__ xs,    // (B,T) flat = bt order
    float*       __restrict__ gxT)   // (3072, 4096)
{
    extern __shared__ char l[];
    float* rowL = (float*)l;              // 32000 floats
    int*   tokL = (int*)(l + V_ * 4);     // 4096 ints
    const int tid = threadIdx.x;
    const int r   = (int)blockIdx.x;

    for (int i = tid; i < NBT; i += 1024) tokL[i] = xs[i];
    const float4* src = (const float4*)(Wih + (size_t)r * V_);
    for (int i = tid; i < V_ / 4; i += 1024) ((float4*)rowL)[i] = src[i];
    __syncthreads();

    const float bias = bih[r];
    float* dst = gxT + (size_t)r * NBT;
    for (int i = tid; i < NBT; i += 1024) dst[i] = rowL[tokL[i]] + bias;
}

// ---------- transpose: gx2[bt][r] = gxT[r][bt] (LDS-tiled 32x32) ----------
__global__ __launch_bounds__(256) void gru_tr(
    const float* __restrict__ gxT,   // (3072, 4096)
    float*       __restrict__ gx2)   // (4096, 3072)
{
    __shared__ float tile[32][33];
    const int tx = threadIdx.x & 31;
    const int ty = threadIdx.x >> 5;
    const int c0 = (int)blockIdx.x * 32;   // bt tile
    const int r0 = (int)blockIdx.y * 32;   // row tile
    #pragma unroll
    for (int ii = 0; ii < 4; ++ii) {
        const int i = ty + ii * 8;
        tile[i][tx] = gxT[(size_t)(r0 + i) * NBT + c0 + tx];
    }
    __syncthreads();
    #pragma unroll
    for (int ii = 0; ii < 4; ++ii) {
        const int i = ty + ii * 8;
        gx2[(size_t)(c0 + i) * G3H + r0 + tx] = tile[tx][i];
    }
}

// ---------- persistent recurrent kernel (round-8 core, gx from gx2) ----------
__global__ __launch_bounds__(NTHR) void gru_persist(
    const float* __restrict__ Whh,   // (3072,1024)
    const float* __restrict__ bhh,   // (3072)
    const float* __restrict__ gx2,   // (4096,3072) = gx[bt][row]
    unsigned*    __restrict__ hpk,   // T_ x (B,H) packed (hi16|lo16) h buffers
    int*         __restrict__ flags, // (NBLK*32) zeroed before launch
    float*       __restrict__ outp,  // (B,T,H)
    float*       __restrict__ hidout)// (B,H)
{
    extern __shared__ char lds[];
    char*  hhi = lds + LDS_HHI;
    char*  hlo = lds + LDS_HLO;
    float* ghp = (float*)(lds + LDS_GHP);

    const int tid  = threadIdx.x;
    const int bid  = (int)blockIdx.x;
    const int j0   = bid * JB;
    const int lane = tid & 63;
    const int wid  = tid >> 6;         // 0..11
    const int g    = wid >> 2;         // gate 0..2
    const int bh   = (wid >> 1) & 1;   // batch half
    const int kh   = wid & 1;          // k half

    // ---- W A-fragments -> registers, once ----
    short8 wAhi[16], wAlo[16];
    {
        const int   arow = lane & 15;
        const int   q    = lane >> 4;
        const float* wr  = Whh + (size_t)(g * H_ + j0 + arow) * H_;
        #pragma unroll
        for (int kkl = 0; kkl < 16; ++kkl) {
            const int kk = kh * 16 + kkl;
            const float4 w0 = *(const float4*)(wr + kk * 32 + q * 8);
            const float4 w1 = *(const float4*)(wr + kk * 32 + q * 8 + 4);
            const float wv[8] = {w0.x, w0.y, w0.z, w0.w, w1.x, w1.y, w1.z, w1.w};
            short8 hi8, lo8;
            #pragma unroll
            for (int j = 0; j < 8; ++j) {
                const unsigned short h = bf16_rtn(wv[j]);
                const float hf = __uint_as_float((unsigned)h << 16);
                hi8[j] = (short)h;
                lo8[j] = (short)bf16_rtn(wv[j] - hf);
            }
            wAhi[kkl] = hi8;
            wAlo[kkl] = lo8;
        }
    }

    // ---- B-frag LDS addressing constants ----
    const int brow  = bh * 16 + (lane & 15);
    const int bq    = lane >> 4;
    const int bbase = brow * 2048;
    const int bhash = (lane & 7) << 4;

    // ---- gate-thread constants (tid<512): jj = tid&15 col, b = tid>>4 ----
    const int jj = tid & 15;
    const int b  = tid >> 4;
    float bhh0 = 0.f, bhh1 = 0.f, bhh2 = 0.f;
    float nxg0 = 0.f, nxg1 = 0.f, nxg2 = 0.f;
    float hold = 0.f;
    if (tid < 512) {
        bhh0 = bhh[0 * H_ + j0 + jj];
        bhh1 = bhh[1 * H_ + j0 + jj];
        bhh2 = bhh[2 * H_ + j0 + jj];
        // t=0 gx prefetch (coalesced 64B per 16-thread group, L3-resident)
        const float* gp = gx2 + (size_t)(b * T_) * G3H + j0 + jj;
        nxg0 = gp[0 * H_];
        nxg1 = gp[1 * H_];
        nxg2 = gp[2 * H_];
    }

    __syncthreads();

    #pragma unroll 1
    for (int t = 0; t < T_; ++t) {
        const unsigned* hp_prev = hpk + (size_t)(t - 1) * BH_;  // valid t>0
        unsigned*       hp_cur  = hpk + (size_t)t * BH_;

        // consume this step's gx; issue next step's (full step of cover)
        const float cg0 = nxg0, cg1 = nxg1, cg2 = nxg2;
        if (tid < 512 && t + 1 < T_) {
            const float* gp = gx2 + (size_t)(b * T_ + t + 1) * G3H + j0 + jj;
            nxg0 = gp[0 * H_];
            nxg1 = gp[1 * H_];
            nxg2 = gp[2 * H_];
        }

        if (t > 0) {
            // ---- rendezvous: 1 thread per producer flag (64 flags) ----
            if (tid < 64) {
                const int* fp = flags + tid * 32;
                int v;
                do {
                    v = __hip_atomic_load(fp, __ATOMIC_RELAXED,
                                          __HIP_MEMORY_SCOPE_AGENT);
                } while (v < t);
            }
            __syncthreads();

            // ---- stage packed h -> swizzled split-bf16 LDS ----
            uint4 st[11];
            #pragma unroll
            for (int i = 0; i < 11; ++i) {
                const int c = tid + i * NTHR;
                if (c < 8192) st[i] = ((const uint4*)hp_prev)[c];
            }
            #pragma unroll
            for (int i = 0; i < 11; ++i) {
                const int c = tid + i * NTHR;
                if (c < 8192) {
                    const int bb  = c >> 8;
                    const int k0  = (c & 255) * 4;
                    const int off = bb * 2048 + ((k0 * 2) ^ ((bb & 7) << 4));
                    short4v hi4, lo4;
                    hi4[0] = (short)(st[i].x >> 16); lo4[0] = (short)(st[i].x & 0xFFFFu);
                    hi4[1] = (short)(st[i].y >> 16); lo4[1] = (short)(st[i].y & 0xFFFFu);
                    hi4[2] = (short)(st[i].z >> 16); lo4[2] = (short)(st[i].z & 0xFFFFu);
                    hi4[3] = (short)(st[i].w >> 16); lo4[3] = (short)(st[i].w & 0xFFFFu);
                    *(short4v*)(hhi + off) = hi4;
                    *(short4v*)(hlo + off) = lo4;
                }
            }
            __syncthreads();
        }

        // ---- MFMA: 3 passes split-bf16, 16 k-steps per wave (k-half) ----
        f32x4 ahh = {0.f, 0.f, 0.f, 0.f};
        f32x4 ahl = {0.f, 0.f, 0.f, 0.f};
        f32x4 alh = {0.f, 0.f, 0.f, 0.f};
        if (t > 0) {
            #pragma unroll
            for (int kkl = 0; kkl < 16; ++kkl) {
                const int kk  = kh * 16 + kkl;
                const int off = (kk * 64 + bq * 16) ^ bhash;
                const short8 bhi8 = *(const short8*)(hhi + bbase + off);
                const short8 blo8 = *(const short8*)(hlo + bbase + off);
                ahh = __builtin_amdgcn_mfma_f32_16x16x32_bf16(wAhi[kkl], bhi8, ahh, 0, 0, 0);
                ahl = __builtin_amdgcn_mfma_f32_16x16x32_bf16(wAhi[kkl], blo8, ahl, 0, 0, 0);
                alh = __builtin_amdgcn_mfma_f32_16x16x32_bf16(wAlo[kkl], bhi8, alh, 0, 0, 0);
            }
        }

        // ---- k-half partials -> LDS ----
        {
            const int bcol = bh * 16 + (lane & 15);
            #pragma unroll
            for (int r = 0; r < 4; ++r) {
                const int m = (lane >> 4) * 4 + r;
                ghp[kh * 1584 + (g * 16 + m) * 33 + bcol] = ahh[r] + ahl[r] + alh[r];
            }
        }
        __syncthreads();

        // ---- gate math + publish (threads 0..511) ----
        if (tid < 512) {
            float hr = bhh0, hz = bhh1, hn = bhh2;
            if (t > 0) {
                hr += ghp[(0 * 16 + jj) * 33 + b] + ghp[1584 + (0 * 16 + jj) * 33 + b];
                hz += ghp[(1 * 16 + jj) * 33 + b] + ghp[1584 + (1 * 16 + jj) * 33 + b];
                hn += ghp[(2 * 16 + jj) * 33 + b] + ghp[1584 + (2 * 16 + jj) * 33 + b];
            }
            const float rg = 1.f / (1.f + __expf(-(cg0 + hr)));
            const float zg = 1.f / (1.f + __expf(-(cg1 + hz)));
            const float tn = cg2 + rg * hn;
            const float e  = __expf(-2.f * fabsf(tn));
            const float m  = (1.f - e) / (1.f + e);
            const float ng = copysignf(m, tn);           // tanh, inf-safe
            const float hnew = (1.f - zg) * ng + zg * hold;
            hold = hnew;                                  // h_old stays in-register

            const unsigned short hh = bf16_rtn(hnew);
            const float hf = __uint_as_float((unsigned)hh << 16);
            const unsigned short hl = bf16_rtn(hnew - hf);
            const unsigned pk = ((unsigned)hh << 16) | (unsigned)hl;
            __hip_atomic_store(hp_cur + (size_t)b * H_ + j0 + jj, pk,
                               __ATOMIC_RELAXED, __HIP_MEMORY_SCOPE_AGENT);
            outp[((size_t)b * T_ + t) * H_ + j0 + jj] = hnew;
            if (t == T_ - 1) hidout[(size_t)b * H_ + j0 + jj] = hnew;
        }

        // ---- publish: syncthreads drains sc1 stores, then raise flag ----
        __syncthreads();
        if (tid == 0) {
            __hip_atomic_store(&flags[bid * 32], t + 1,
                               __ATOMIC_RELAXED, __HIP_MEMORY_SCOPE_AGENT);
        }
    }
}

extern "C" void kernel_launch(void* const* d_in, const int* in_sizes, int n_in,
                              void* d_out, int out_size, void* d_ws, size_t ws_size,
                              hipStream_t stream) {
    const int*   xs  = (const int*)  d_in[0];
    const float* Wih = (const float*)d_in[1];
    const float* Whh = (const float*)d_in[2];
    const float* bih = (const float*)d_in[3];
    const float* bhh = (const float*)d_in[4];

    float* outp = (float*)d_out;
    float* hid  = outp + (size_t)B_ * T_ * H_;

    unsigned* hpk   = (unsigned*)d_ws;                       // 16 MB
    int*      flags = (int*)(hpk + (size_t)T_ * BH_);        // 8 KB
    float*    gxT   = (float*)(flags + NBLK * 32);           // 50 MB
    float*    gx2   = gxT + (size_t)G3H * NBT;               // 50 MB

    (void)hipMemsetAsync(flags, 0, (size_t)NBLK * 32 * sizeof(int), stream);

    (void)hipFuncSetAttribute((const void*)gru_embed,
                              hipFuncAttributeMaxDynamicSharedMemorySize,
                              (int)EMB_LDS);
    (void)hipFuncSetAttribute((const void*)gru_persist,
                              hipFuncAttributeMaxDynamicSharedMemorySize,
                              (int)LDS_BYTES);

    gru_embed<<<G3H, 1024, EMB_LDS, stream>>>(Wih, bih, xs, gxT);
    gru_tr<<<dim3(NBT / 32, G3H / 32), 256, 0, stream>>>(gxT, gx2);
    gru_persist<<<NBLK, NTHR, LDS_BYTES, stream>>>(
        Whh, bhh, gx2, hpk, flags, outp, hid);

    (void)in_sizes; (void)n_in; (void)out_size; (void)ws_size;
}